// Round 1
// baseline (321.702 us; speedup 1.0000x reference)
//
#include <hip/hip_runtime.h>

namespace {

constexpr int Hh = 128, Ww = 128, HW = 128 * 128;
constexpr int Cin = 64, HID = 16, OC = 18;

// ---------------- offset branch ----------------

__global__ __launch_bounds__(256) void k_conv1(
    const float* __restrict__ x, const float* __restrict__ w,
    const float* __restrict__ g, const float* __restrict__ bb,
    const float* __restrict__ m, const float* __restrict__ v,
    float* __restrict__ f) {
  int t = blockIdx.x * 256 + threadIdx.x;  // pixel id over B*H*W = 32768
  int b = t >> 14, hw = t & (HW - 1);
  const float* xb = x + b * Cin * HW + hw;
  float acc[HID];
#pragma unroll
  for (int o = 0; o < HID; ++o) acc[o] = 0.f;
  for (int c = 0; c < Cin; ++c) {
    float xv = xb[c * HW];
#pragma unroll
    for (int o = 0; o < HID; ++o) acc[o] = fmaf(w[o * Cin + c], xv, acc[o]);
  }
  float* fb = f + b * HID * HW + hw;
#pragma unroll
  for (int o = 0; o < HID; ++o) {
    float inv = g[o] / sqrtf(v[o] + 1e-5f);
    float y = fmaf(acc[o], inv, bb[o] - m[o] * inv);
    fb[o * HW] = fmaxf(y, 0.f);
  }
}

__global__ __launch_bounds__(256) void k_conv2(
    const float* __restrict__ f, const float* __restrict__ w,
    const float* __restrict__ g, const float* __restrict__ bb,
    const float* __restrict__ m, const float* __restrict__ v,
    float* __restrict__ offa) {
  int t = blockIdx.x * 256 + threadIdx.x;
  int b = t >> 14, hw = t & (HW - 1);
  int h = hw >> 7, wc = hw & 127;
  float acc[OC];
#pragma unroll
  for (int o = 0; o < OC; ++o) acc[o] = 0.f;
  const float* fb = f + b * HID * HW;
  for (int c = 0; c < HID; ++c) {
    const float* fc = fb + c * HW;
#pragma unroll
    for (int dh = -1; dh <= 1; ++dh) {
      int hh = h + dh;
      if ((unsigned)hh >= (unsigned)Hh) continue;
#pragma unroll
      for (int dw = -1; dw <= 1; ++dw) {
        int ww = wc + dw;
        if ((unsigned)ww >= (unsigned)Ww) continue;
        float fv = fc[hh * Ww + ww];
        int kk = (dh + 1) * 3 + (dw + 1);
#pragma unroll
        for (int o = 0; o < OC; ++o)
          acc[o] = fmaf(w[(o * HID + c) * 9 + kk], fv, acc[o]);
      }
    }
  }
  float* ob = offa + b * OC * HW + hw;
#pragma unroll
  for (int o = 0; o < OC; ++o) {
    float inv = g[o] / sqrtf(v[o] + 1e-5f);
    float y = fmaf(acc[o], inv, bb[o] - m[o] * inv);
    ob[o * HW] = fmaxf(y, 0.f);
  }
}

__global__ __launch_bounds__(256) void k_conv3(
    const float* __restrict__ offa, const float* __restrict__ w,
    const float* __restrict__ g, const float* __restrict__ bb,
    const float* __restrict__ m, const float* __restrict__ v,
    float* __restrict__ offb) {
  int t = blockIdx.x * 256 + threadIdx.x;
  int b = t >> 14, hw = t & (HW - 1);
  const float* ob = offa + b * OC * HW + hw;
  float in[OC];
#pragma unroll
  for (int c = 0; c < OC; ++c) in[c] = ob[c * HW];
  float* dst = offb + t * 18;  // [pix][18] pixel-major
#pragma unroll
  for (int o = 0; o < OC; ++o) {
    float acc = 0.f;
#pragma unroll
    for (int c = 0; c < OC; ++c) acc = fmaf(w[o * OC + c], in[c], acc);
    float inv = g[o] / sqrtf(v[o] + 1e-5f);
    float y = fmaf(acc, inv, bb[o] - m[o] * inv);
    dst[o] = fmaxf(y, 0.f);
  }
}

// transpose w_out [oc][576] -> wt [k/4][oc][4] for coalesced lane loads
__global__ __launch_bounds__(256) void k_wt(const float* __restrict__ w,
                                            float* __restrict__ wt) {
  int t = blockIdx.x * 256 + threadIdx.x;  // 36864 total
  int oc = t / 576, k = t % 576;
  wt[(k >> 2) * 256 + oc * 4 + (k & 3)] = w[t];
}

// ---------------- fused gather + matmul + identity ----------------
// block = 16 consecutive pixels (same batch, same row). 2048 blocks.

__global__ __launch_bounds__(256) void k_main(
    const float* __restrict__ x, const float* __restrict__ offb,
    const float* __restrict__ wt, float* __restrict__ out) {
  __shared__ float A[16][584];      // 584 pad: write conflicts ~2-way (free)
  __shared__ float sg[16][9][4];
  __shared__ int si[16][9][4];
  const int blk = blockIdx.x;
  const int b = blk >> 10;          // 1024 blocks per batch image
  const int t = threadIdx.x;

  // phase 0: per (pixel, sampling point): 4 corner offsets + bilinear weights
  if (t < 144) {
    const int p = t / 9, n = t % 9;
    const int pix = blk * 16 + p;
    const int hw = pix & (HW - 1);
    const int h = hw >> 7, wc = hw & 127;
    const float offx = offb[pix * 18 + n];
    const float offy = offb[pix * 18 + 9 + n];
    const float px = (float)(h + (n / 3)) + offx;        // h+1 + (n/3 - 1)
    const float py = (float)(wc + (n % 3)) + offy;       // w+1 + (n%3 - 1)
    const float flx = floorf(px), fly = floorf(py);
    const float qltxf = fminf(fmaxf(flx, 0.f), 129.f);
    const float qltyf = fminf(fmaxf(fly, 0.f), 129.f);
    const float qrbxf = fminf(fmaxf(flx + 1.f, 0.f), 129.f);
    const float qrbyf = fminf(fmaxf(fly + 1.f, 0.f), 129.f);
    const float pxc = fminf(fmaxf(px, 0.f), 129.f);
    const float pyc = fminf(fmaxf(py, 0.f), 129.f);
    const float wx_lt = 1.f + (qltxf - pxc);
    const float wx_rb = 1.f - (qrbxf - pxc);
    const float wy_lt = 1.f + (qltyf - pyc);
    const float wy_rb = 1.f - (qrbyf - pyc);
    const int qltx = (int)qltxf, qlty = (int)qltyf;
    const int qrbx = (int)qrbxf, qrby = (int)qrbyf;
    const int cx[4] = {qltx, qrbx, qltx, qrbx};
    const int cy[4] = {qlty, qrby, qrby, qlty};
    const float gw[4] = {wx_lt * wy_lt, wx_rb * wy_rb, wx_lt * wy_rb,
                         wx_rb * wy_lt};
#pragma unroll
    for (int cc = 0; cc < 4; ++cc) {
      // padded border of xp is zero -> fold into weight=0
      const bool valid =
          (cx[cc] >= 1) && (cx[cc] <= 128) && (cy[cc] >= 1) && (cy[cc] <= 128);
      si[p][n][cc] = valid ? ((cx[cc] - 1) * Ww + (cy[cc] - 1)) : 0;
      sg[p][n][cc] = valid ? gw[cc] : 0.f;
    }
  }
  __syncthreads();

  // phase 1: gather + blend A[pixel][ic*9+n]
  {
    const int p = t >> 4, icg = t & 15;
    const float* xb = x + b * Cin * HW;
#pragma unroll
    for (int j = 0; j < 4; ++j) {
      const int ic = icg + j * 16;
      const float* xc = xb + ic * HW;
#pragma unroll
      for (int n = 0; n < 9; ++n) {
        float s = sg[p][n][0] * xc[si[p][n][0]];
        s = fmaf(sg[p][n][1], xc[si[p][n][1]], s);
        s = fmaf(sg[p][n][2], xc[si[p][n][2]], s);
        s = fmaf(sg[p][n][3], xc[si[p][n][3]], s);
        A[p][ic * 9 + n] = s;
      }
    }
  }
  __syncthreads();

  // phase 2: out[pix][oc] = dot(A[pix][:], w_out[oc][:]) + identity
  {
    const int oc = t & 63, pg = t >> 6;  // wave-uniform pg -> LDS broadcast
    const float* wp = wt + oc * 4;
    float a0 = 0.f, a1 = 0.f, a2 = 0.f, a3 = 0.f;
    for (int k4 = 0; k4 < 144; ++k4) {
      const float4 wv = *(const float4*)(wp + k4 * 256);
      const float4 x0 = *(const float4*)&A[pg][k4 * 4];
      const float4 x1 = *(const float4*)&A[pg + 4][k4 * 4];
      const float4 x2 = *(const float4*)&A[pg + 8][k4 * 4];
      const float4 x3 = *(const float4*)&A[pg + 12][k4 * 4];
      a0 = fmaf(wv.x, x0.x, a0); a0 = fmaf(wv.y, x0.y, a0);
      a0 = fmaf(wv.z, x0.z, a0); a0 = fmaf(wv.w, x0.w, a0);
      a1 = fmaf(wv.x, x1.x, a1); a1 = fmaf(wv.y, x1.y, a1);
      a1 = fmaf(wv.z, x1.z, a1); a1 = fmaf(wv.w, x1.w, a1);
      a2 = fmaf(wv.x, x2.x, a2); a2 = fmaf(wv.y, x2.y, a2);
      a2 = fmaf(wv.z, x2.z, a2); a2 = fmaf(wv.w, x2.w, a2);
      a3 = fmaf(wv.x, x3.x, a3); a3 = fmaf(wv.y, x3.y, a3);
      a3 = fmaf(wv.z, x3.z, a3); a3 = fmaf(wv.w, x3.w, a3);
    }
    const int base = (b * Cin + oc) * HW;
    const int hw0 = (blk * 16) & (HW - 1);
    out[base + hw0 + pg] = x[base + hw0 + pg] + a0;
    out[base + hw0 + pg + 4] = x[base + hw0 + pg + 4] + a1;
    out[base + hw0 + pg + 8] = x[base + hw0 + pg + 8] + a2;
    out[base + hw0 + pg + 12] = x[base + hw0 + pg + 12] + a3;
  }
}

}  // namespace

extern "C" void kernel_launch(void* const* d_in, const int* in_sizes, int n_in,
                              void* d_out, int out_size, void* d_ws,
                              size_t ws_size, hipStream_t stream) {
  const float* x = (const float*)d_in[0];
  const float* w1 = (const float*)d_in[1];
  const float* g1 = (const float*)d_in[2];
  const float* b1 = (const float*)d_in[3];
  const float* m1 = (const float*)d_in[4];
  const float* v1 = (const float*)d_in[5];
  const float* wdw = (const float*)d_in[6];
  const float* g2 = (const float*)d_in[7];
  const float* b2 = (const float*)d_in[8];
  const float* m2 = (const float*)d_in[9];
  const float* v2 = (const float*)d_in[10];
  const float* w2 = (const float*)d_in[11];
  const float* g3 = (const float*)d_in[12];
  const float* b3 = (const float*)d_in[13];
  const float* m3 = (const float*)d_in[14];
  const float* v3 = (const float*)d_in[15];
  const float* wout = (const float*)d_in[16];
  float* out = (float*)d_out;

  char* ws = (char*)d_ws;
  float* f = (float*)(ws);                               // 2*16*16384*4 = 2 MB
  float* offa = (float*)(ws + 2097152);                  // 2*18*16384*4
  float* offb = (float*)(ws + 2097152 + 2359296);        // 2*16384*18*4
  float* wt = (float*)(ws + 2097152 + 2359296 + 2359296);// 576*64*4

  k_conv1<<<128, 256, 0, stream>>>(x, w1, g1, b1, m1, v1, f);
  k_conv2<<<128, 256, 0, stream>>>(f, wdw, g2, b2, m2, v2, offa);
  k_conv3<<<128, 256, 0, stream>>>(offa, w2, g3, b3, m3, v3, offb);
  k_wt<<<144, 256, 0, stream>>>(wout, wt);
  k_main<<<2048, 256, 0, stream>>>(x, offb, wt, out);
}

// Round 2
// 185.771 us; speedup vs baseline: 1.7317x; 1.7317x over previous
//
#include <hip/hip_runtime.h>

namespace {

constexpr int Hh = 128, Ww = 128, HW = 128 * 128;
constexpr int Cin = 64, HID = 16, OC = 18;

typedef __attribute__((ext_vector_type(8))) short short8;
typedef __attribute__((ext_vector_type(4))) float f32x4;

__device__ __forceinline__ unsigned short f2bf(float f) {
  unsigned u = __builtin_bit_cast(unsigned, f);
  unsigned rounded = u + 0x7fffu + ((u >> 16) & 1u);
  return (unsigned short)(rounded >> 16);
}
__device__ __forceinline__ float bf2f(unsigned short s) {
  unsigned u = ((unsigned)s) << 16;
  return __builtin_bit_cast(float, u);
}

// ---------------- offset branch ----------------

__global__ __launch_bounds__(64) void k_conv1(
    const float* __restrict__ x, const float* __restrict__ w,
    const float* __restrict__ g, const float* __restrict__ bb,
    const float* __restrict__ m, const float* __restrict__ v,
    float* __restrict__ f) {
  int t = blockIdx.x * 64 + threadIdx.x;  // pixel id over B*H*W = 32768
  int b = t >> 14, hw = t & (HW - 1);
  const float* xb = x + b * Cin * HW + hw;
  float acc[HID];
#pragma unroll
  for (int o = 0; o < HID; ++o) acc[o] = 0.f;
  for (int c = 0; c < Cin; ++c) {
    float xv = xb[c * HW];
#pragma unroll
    for (int o = 0; o < HID; ++o) acc[o] = fmaf(w[o * Cin + c], xv, acc[o]);
  }
  float* fb = f + b * HID * HW + hw;
#pragma unroll
  for (int o = 0; o < HID; ++o) {
    float inv = g[o] / sqrtf(v[o] + 1e-5f);
    float y = fmaf(acc[o], inv, bb[o] - m[o] * inv);
    fb[o * HW] = fmaxf(y, 0.f);
  }
}

__global__ __launch_bounds__(64) void k_conv2(
    const float* __restrict__ f, const float* __restrict__ w,
    const float* __restrict__ g, const float* __restrict__ bb,
    const float* __restrict__ m, const float* __restrict__ v,
    float* __restrict__ offa) {
  int t = blockIdx.x * 64 + threadIdx.x;
  int b = t >> 14, hw = t & (HW - 1);
  int h = hw >> 7, wc = hw & 127;
  float acc[OC];
#pragma unroll
  for (int o = 0; o < OC; ++o) acc[o] = 0.f;
  const float* fb = f + b * HID * HW;
  for (int c = 0; c < HID; ++c) {
    const float* fc = fb + c * HW;
#pragma unroll
    for (int dh = -1; dh <= 1; ++dh) {
      int hh = h + dh;
      if ((unsigned)hh >= (unsigned)Hh) continue;
#pragma unroll
      for (int dw = -1; dw <= 1; ++dw) {
        int ww = wc + dw;
        if ((unsigned)ww >= (unsigned)Ww) continue;
        float fv = fc[hh * Ww + ww];
        int kk = (dh + 1) * 3 + (dw + 1);
#pragma unroll
        for (int o = 0; o < OC; ++o)
          acc[o] = fmaf(w[(o * HID + c) * 9 + kk], fv, acc[o]);
      }
    }
  }
  float* ob = offa + b * OC * HW + hw;
#pragma unroll
  for (int o = 0; o < OC; ++o) {
    float inv = g[o] / sqrtf(v[o] + 1e-5f);
    float y = fmaf(acc[o], inv, bb[o] - m[o] * inv);
    ob[o * HW] = fmaxf(y, 0.f);
  }
}

__global__ __launch_bounds__(64) void k_conv3(
    const float* __restrict__ offa, const float* __restrict__ w,
    const float* __restrict__ g, const float* __restrict__ bb,
    const float* __restrict__ m, const float* __restrict__ v,
    float* __restrict__ offb) {
  int t = blockIdx.x * 64 + threadIdx.x;
  int b = t >> 14, hw = t & (HW - 1);
  const float* ob = offa + b * OC * HW + hw;
  float in[OC];
#pragma unroll
  for (int c = 0; c < OC; ++c) in[c] = ob[c * HW];
  float* dst = offb + t * 18;  // [pix][18] pixel-major
#pragma unroll
  for (int o = 0; o < OC; ++o) {
    float acc = 0.f;
#pragma unroll
    for (int c = 0; c < OC; ++c) acc = fmaf(w[o * OC + c], in[c], acc);
    float inv = g[o] / sqrtf(v[o] + 1e-5f);
    float y = fmaf(acc, inv, bb[o] - m[o] * inv);
    dst[o] = fmaxf(y, 0.f);
  }
}

// w_out [oc][ic*9+n] fp32 -> wtb bf16 [oc][n*64+ic]
__global__ __launch_bounds__(256) void k_wtb(const float* __restrict__ w,
                                             unsigned short* __restrict__ wtb) {
  int t = blockIdx.x * 256 + threadIdx.x;  // 36864
  int oc = t / 576, r = t % 576;
  int n = r >> 6, ic = r & 63;
  wtb[oc * 576 + r] = f2bf(w[oc * 576 + ic * 9 + n]);
}

// x [B,C,H,W] fp32 -> xT [B,H*W,C] bf16 (tile transpose via LDS)
__global__ __launch_bounds__(256) void k_xt(const float* __restrict__ x,
                                            unsigned short* __restrict__ xT) {
  __shared__ float T[64][65];
  const int blk = blockIdx.x;          // 512 = 2 * 256
  const int b = blk >> 8;
  const int hw0 = (blk & 255) * 64;
  const int t = threadIdx.x;
  {
    const int p = t & 63, cg = t >> 6;  // 4 channel groups of 16
#pragma unroll
    for (int j = 0; j < 16; ++j) {
      const int c = cg * 16 + j;
      T[c][p] = x[(b * Cin + c) * HW + hw0 + p];
    }
  }
  __syncthreads();
  {
    const int c = t & 63, pg = t >> 6;
#pragma unroll
    for (int j = 0; j < 16; ++j) {
      const int p = pg * 16 + j;
      xT[((size_t)(b * HW + hw0 + p)) * 64 + c] = f2bf(T[c][p]);
    }
  }
}

// ---------------- fused gather + MFMA matmul + identity ----------------
// block = 16 consecutive pixels (same batch, same row). 2048 blocks.

__global__ __launch_bounds__(256) void k_main(
    const float* __restrict__ x, const unsigned short* __restrict__ xT,
    const float* __restrict__ offb, const unsigned short* __restrict__ wtb,
    float* __restrict__ out) {
  __shared__ unsigned short A[16][584];  // bf16, K' = n*64+ic, pad row to 584
  __shared__ float sg[16][9][4];
  __shared__ int si[16][9][4];
  const int blk = blockIdx.x;
  const int b = blk >> 10;  // 1024 blocks per batch image
  const int t = threadIdx.x;
  const int hw0 = (blk & 1023) * 16;

  // phase 0: per (pixel, sampling point): 4 corner pixel-indices + weights
  if (t < 144) {
    const int p = t / 9, n = t % 9;
    const int pix = blk * 16 + p;
    const int hw = pix & (HW - 1);
    const int h = hw >> 7, wc = hw & 127;
    const float offx = offb[pix * 18 + n];
    const float offy = offb[pix * 18 + 9 + n];
    const float px = (float)(h + (n / 3)) + offx;   // h+1 + (n/3 - 1)
    const float py = (float)(wc + (n % 3)) + offy;  // w+1 + (n%3 - 1)
    const float flx = floorf(px), fly = floorf(py);
    const float qltxf = fminf(fmaxf(flx, 0.f), 129.f);
    const float qltyf = fminf(fmaxf(fly, 0.f), 129.f);
    const float qrbxf = fminf(fmaxf(flx + 1.f, 0.f), 129.f);
    const float qrbyf = fminf(fmaxf(fly + 1.f, 0.f), 129.f);
    const float pxc = fminf(fmaxf(px, 0.f), 129.f);
    const float pyc = fminf(fmaxf(py, 0.f), 129.f);
    const float wx_lt = 1.f + (qltxf - pxc);
    const float wx_rb = 1.f - (qrbxf - pxc);
    const float wy_lt = 1.f + (qltyf - pyc);
    const float wy_rb = 1.f - (qrbyf - pyc);
    const int qltx = (int)qltxf, qlty = (int)qltyf;
    const int qrbx = (int)qrbxf, qrby = (int)qrbyf;
    const int cx[4] = {qltx, qrbx, qltx, qrbx};
    const int cy[4] = {qlty, qrby, qrby, qlty};
    const float gw[4] = {wx_lt * wy_lt, wx_rb * wy_rb, wx_lt * wy_rb,
                         wx_rb * wy_lt};
#pragma unroll
    for (int cc = 0; cc < 4; ++cc) {
      const bool valid =
          (cx[cc] >= 1) && (cx[cc] <= 128) && (cy[cc] >= 1) && (cy[cc] <= 128);
      si[p][n][cc] = valid ? ((cx[cc] - 1) * Ww + (cy[cc] - 1)) : 0;
      sg[p][n][cc] = valid ? gw[cc] : 0.f;
    }
  }
  __syncthreads();

  // phase 1: gather + blend -> A[pixel][n*64+ic] (bf16x4 contiguous writes)
  {
    const int p = t >> 4, ch4 = t & 15;  // chunk = channels [ch4*4, ch4*4+4)
    const unsigned short* xb = xT + ((size_t)b * HW) * 64 + ch4 * 4;
#pragma unroll
    for (int n = 0; n < 9; ++n) {
      const ushort4 u0 = *(const ushort4*)(xb + (size_t)si[p][n][0] * 64);
      const ushort4 u1 = *(const ushort4*)(xb + (size_t)si[p][n][1] * 64);
      const ushort4 u2 = *(const ushort4*)(xb + (size_t)si[p][n][2] * 64);
      const ushort4 u3 = *(const ushort4*)(xb + (size_t)si[p][n][3] * 64);
      const float g0 = sg[p][n][0], g1 = sg[p][n][1], g2 = sg[p][n][2],
                  g3 = sg[p][n][3];
      float r0 = g0 * bf2f(u0.x);
      float r1 = g0 * bf2f(u0.y);
      float r2 = g0 * bf2f(u0.z);
      float r3 = g0 * bf2f(u0.w);
      r0 = fmaf(g1, bf2f(u1.x), r0); r1 = fmaf(g1, bf2f(u1.y), r1);
      r2 = fmaf(g1, bf2f(u1.z), r2); r3 = fmaf(g1, bf2f(u1.w), r3);
      r0 = fmaf(g2, bf2f(u2.x), r0); r1 = fmaf(g2, bf2f(u2.y), r1);
      r2 = fmaf(g2, bf2f(u2.z), r2); r3 = fmaf(g2, bf2f(u2.w), r3);
      r0 = fmaf(g3, bf2f(u3.x), r0); r1 = fmaf(g3, bf2f(u3.y), r1);
      r2 = fmaf(g3, bf2f(u3.z), r2); r3 = fmaf(g3, bf2f(u3.w), r3);
      ushort4 o;
      o.x = f2bf(r0); o.y = f2bf(r1); o.z = f2bf(r2); o.w = f2bf(r3);
      *(ushort4*)&A[p][n * 64 + ch4 * 4] = o;
    }
  }
  __syncthreads();

  // phase 2: MFMA. D[oc 16][pixel 16] per wave; A-op = weights, B-op = pixels.
  {
    const int wv = t >> 6;      // wave -> oc tile [wv*16, wv*16+16)
    const int lane = t & 63;
    const int l15 = lane & 15;  // A: m=oc offset; B: n=pixel
    const int quad = lane >> 4;
    const unsigned short* wrow = wtb + (size_t)(wv * 16 + l15) * 576 + quad * 8;
    const unsigned short* arow = &A[l15][quad * 8];
    f32x4 acc = {0.f, 0.f, 0.f, 0.f};
#pragma unroll
    for (int kb = 0; kb < 18; ++kb) {
      short8 af = *(const short8*)(wrow + kb * 32);
      short8 bf = *(const short8*)(arow + kb * 32);
      acc = __builtin_amdgcn_mfma_f32_16x16x32_bf16(af, bf, acc, 0, 0, 0);
    }
    // D row = oc = wv*16 + quad*4 + r, col = pixel = l15
#pragma unroll
    for (int r = 0; r < 4; ++r) {
      const int oc = wv * 16 + quad * 4 + r;
      const size_t idx = ((size_t)(b * Cin + oc)) * HW + hw0 + l15;
      out[idx] = x[idx] + acc[r];
    }
  }
}

}  // namespace

extern "C" void kernel_launch(void* const* d_in, const int* in_sizes, int n_in,
                              void* d_out, int out_size, void* d_ws,
                              size_t ws_size, hipStream_t stream) {
  const float* x = (const float*)d_in[0];
  const float* w1 = (const float*)d_in[1];
  const float* g1 = (const float*)d_in[2];
  const float* b1 = (const float*)d_in[3];
  const float* m1 = (const float*)d_in[4];
  const float* v1 = (const float*)d_in[5];
  const float* wdw = (const float*)d_in[6];
  const float* g2 = (const float*)d_in[7];
  const float* b2 = (const float*)d_in[8];
  const float* m2 = (const float*)d_in[9];
  const float* v2 = (const float*)d_in[10];
  const float* w2 = (const float*)d_in[11];
  const float* g3 = (const float*)d_in[12];
  const float* b3 = (const float*)d_in[13];
  const float* m3 = (const float*)d_in[14];
  const float* v3 = (const float*)d_in[15];
  const float* wout = (const float*)d_in[16];
  float* out = (float*)d_out;

  char* ws = (char*)d_ws;
  unsigned short* wtb = (unsigned short*)ws;                   // 73,728 B
  unsigned short* xT = (unsigned short*)(ws + 81920);          // 4,194,304 B
  float* f = (float*)(ws + 81920 + 4194304);                   // 2,097,152 B
  float* offa = (float*)(ws + 81920 + 4194304 + 2097152);      // 2,359,296 B
  float* offb = (float*)(ws + 81920 + 4194304 + 2097152 + 2359296);

  k_wtb<<<144, 256, 0, stream>>>(wout, wtb);
  k_xt<<<512, 256, 0, stream>>>(x, xT);
  k_conv1<<<512, 64, 0, stream>>>(x, w1, g1, b1, m1, v1, f);
  k_conv2<<<512, 64, 0, stream>>>(f, wdw, g2, b2, m2, v2, offa);
  k_conv3<<<512, 64, 0, stream>>>(offa, w2, g3, b3, m3, v3, offb);
  k_main<<<2048, 256, 0, stream>>>(x, xT, offb, wtb, out);
}

// Round 3
// 149.437 us; speedup vs baseline: 2.1528x; 1.2431x over previous
//
#include <hip/hip_runtime.h>

namespace {

constexpr int Hh = 128, Ww = 128, HW = 128 * 128;
constexpr int Cin = 64, HID = 16, OC = 18;

typedef __attribute__((ext_vector_type(8))) short short8;
typedef __attribute__((ext_vector_type(4))) float f32x4;

__device__ __forceinline__ unsigned short f2bf(float f) {
  unsigned u = __builtin_bit_cast(unsigned, f);
  unsigned rounded = u + 0x7fffu + ((u >> 16) & 1u);
  return (unsigned short)(rounded >> 16);
}
__device__ __forceinline__ float bf2f(unsigned short s) {
  unsigned u = ((unsigned)s) << 16;
  return __builtin_bit_cast(float, u);
}

// ---------------- pre: x transpose to bf16 channel-last + weight reorder ----
// blocks [0,512): xT;  blocks [512,656): wtb
__global__ __launch_bounds__(256) void k_pre(const float* __restrict__ x,
                                             unsigned short* __restrict__ xT,
                                             const float* __restrict__ w,
                                             unsigned short* __restrict__ wtb) {
  __shared__ float T[64][65];
  const int blk = blockIdx.x;
  const int t = threadIdx.x;
  if (blk >= 512) {  // w_out [oc][ic*9+n] fp32 -> wtb bf16 [oc][n*64+ic]
    const int i = (blk - 512) * 256 + t;  // 36864 total
    const int oc = i / 576, r = i % 576;
    const int n = r >> 6, ic = r & 63;
    wtb[oc * 576 + r] = f2bf(w[oc * 576 + ic * 9 + n]);
    return;
  }
  const int b = blk >> 8;
  const int hw0 = (blk & 255) * 64;
  {
    const int p = t & 63, cg = t >> 6;
#pragma unroll
    for (int j = 0; j < 16; ++j) {
      const int c = cg * 16 + j;
      T[c][p] = x[(b * Cin + c) * HW + hw0 + p];
    }
  }
  __syncthreads();
  {
    const int c = t & 63, pg = t >> 6;
#pragma unroll
    for (int j = 0; j < 16; ++j) {
      const int p = pg * 16 + j;
      xT[((size_t)(b * HW + hw0 + p)) * 64 + c] = f2bf(T[c][p]);
    }
  }
}

// ---------------- fused offset branch: conv1(1x1)+conv2(3x3)+conv3(1x1) ----
// 512 blocks x 128 threads. Tile = 4 rows x 16 cols; halo 6x18 = 108 px.
__global__ __launch_bounds__(128) void k_off(
    const float* __restrict__ x, const float* __restrict__ w1,
    const float* __restrict__ g1, const float* __restrict__ b1,
    const float* __restrict__ m1, const float* __restrict__ v1,
    const float* __restrict__ wdw, const float* __restrict__ g2,
    const float* __restrict__ b2, const float* __restrict__ m2,
    const float* __restrict__ v2, const float* __restrict__ w2,
    const float* __restrict__ g3, const float* __restrict__ b3,
    const float* __restrict__ m3, const float* __restrict__ v3,
    float* __restrict__ offb) {
  __shared__ float f[HID][108];    // channel-major: conv2 reads stride-1
  __shared__ float off2[64][19];   // odd stride -> conflict-free
  __shared__ float sA[16], bA[16], sB[18], bB[18], sC[18], bC[18];
  const int t = threadIdx.x;
  const int blk = blockIdx.x;          // b*256 + tr*8 + tc
  const int b = blk >> 8;
  const int r0 = ((blk >> 3) & 31) * 4;
  const int c0 = (blk & 7) * 16;

  if (t < 16) {
    float inv = g1[t] * rsqrtf(v1[t] + 1e-5f);
    sA[t] = inv; bA[t] = b1[t] - m1[t] * inv;
  } else if (t < 34) {
    int o = t - 16;
    float inv = g2[o] * rsqrtf(v2[o] + 1e-5f);
    sB[o] = inv; bB[o] = b2[o] - m2[o] * inv;
  } else if (t < 52) {
    int o = t - 34;
    float inv = g3[o] * rsqrtf(v3[o] + 1e-5f);
    sC[o] = inv; bC[o] = b3[o] - m3[o] * inv;
  }
  __syncthreads();

  // phase A: conv1 + BN + ReLU over halo -> f (zero outside image = conv2 pad)
  if (t < 108) {
    const int hp = r0 + t / 18 - 1;
    const int wp = c0 + (t % 18) - 1;
    if ((unsigned)hp < (unsigned)Hh && (unsigned)wp < (unsigned)Ww) {
      const float* xp = x + ((size_t)b * Cin) * HW + hp * Ww + wp;
      float acc[HID];
#pragma unroll
      for (int o = 0; o < HID; ++o) acc[o] = 0.f;
      for (int c = 0; c < Cin; ++c) {
        const float xv = xp[c * HW];
#pragma unroll
        for (int o = 0; o < HID; ++o)
          acc[o] = fmaf(w1[o * Cin + c], xv, acc[o]);
      }
#pragma unroll
      for (int o = 0; o < HID; ++o)
        f[o][t] = fmaxf(fmaf(acc[o], sA[o], bA[o]), 0.f);
    } else {
#pragma unroll
      for (int o = 0; o < HID; ++o) f[o][t] = 0.f;
    }
  }
  __syncthreads();

  const int wave = __builtin_amdgcn_readfirstlane(t >> 6);  // oc half 0/1
  const int lane = t & 63;                                  // pixel in tile
  const int rr = lane >> 4, cc = lane & 15;

  // phase B: conv2(3x3) + BN + ReLU; wave-uniform weights -> scalar loads
  {
    float acc[9];
#pragma unroll
    for (int j = 0; j < 9; ++j) acc[j] = 0.f;
    for (int c = 0; c < HID; ++c) {
      float fv[9];
#pragma unroll
      for (int dh = 0; dh < 3; ++dh)
#pragma unroll
        for (int dw = 0; dw < 3; ++dw)
          fv[dh * 3 + dw] = f[c][(rr + dh) * 18 + cc + dw];
#pragma unroll
      for (int j = 0; j < 9; ++j) {
        const float* wj = wdw + (((wave * 9 + j) * HID + c) * 9);
#pragma unroll
        for (int kk = 0; kk < 9; ++kk) acc[j] = fmaf(wj[kk], fv[kk], acc[j]);
      }
    }
#pragma unroll
    for (int j = 0; j < 9; ++j) {
      const int o = wave * 9 + j;
      off2[lane][o] = fmaxf(fmaf(acc[j], sB[o], bB[o]), 0.f);
    }
  }
  __syncthreads();

  // phase C: conv3(1x1) + BN + ReLU -> offb [pix][18]
  {
    float in[OC];
#pragma unroll
    for (int c = 0; c < OC; ++c) in[c] = off2[lane][c];
    const int hw = (r0 + rr) * Ww + c0 + cc;
    float* dst = offb + ((size_t)(b * HW + hw)) * 18;
#pragma unroll
    for (int j = 0; j < 9; ++j) {
      const int o = wave * 9 + j;
      float a = 0.f;
#pragma unroll
      for (int c = 0; c < OC; ++c) a = fmaf(w2[o * OC + c], in[c], a);
      dst[o] = fmaxf(fmaf(a, sC[o], bC[o]), 0.f);
    }
  }
}

// ---------------- fused gather + MFMA matmul + identity ----------------
// block = 16 consecutive pixels (same batch, same row). 2048 blocks.
__global__ __launch_bounds__(256) void k_main(
    const float* __restrict__ x, const unsigned short* __restrict__ xT,
    const float* __restrict__ offb, const unsigned short* __restrict__ wtb,
    float* __restrict__ out) {
  __shared__ unsigned short A[16][584];  // bf16, K' = n*64+ic
  __shared__ float sg[16][9][4];
  __shared__ int si[16][9][4];
  const int blk = blockIdx.x;
  const int b = blk >> 10;
  const int t = threadIdx.x;
  const int hw0 = (blk & 1023) * 16;

  // phase 0: per (pixel, sampling point): 4 corner pixel-indices + weights
  if (t < 144) {
    const int p = t / 9, n = t % 9;
    const int pix = blk * 16 + p;
    const int hw = pix & (HW - 1);
    const int h = hw >> 7, wc = hw & 127;
    const float offx = offb[pix * 18 + n];
    const float offy = offb[pix * 18 + 9 + n];
    const float px = (float)(h + (n / 3)) + offx;
    const float py = (float)(wc + (n % 3)) + offy;
    const float flx = floorf(px), fly = floorf(py);
    const float qltxf = fminf(fmaxf(flx, 0.f), 129.f);
    const float qltyf = fminf(fmaxf(fly, 0.f), 129.f);
    const float qrbxf = fminf(fmaxf(flx + 1.f, 0.f), 129.f);
    const float qrbyf = fminf(fmaxf(fly + 1.f, 0.f), 129.f);
    const float pxc = fminf(fmaxf(px, 0.f), 129.f);
    const float pyc = fminf(fmaxf(py, 0.f), 129.f);
    const float wx_lt = 1.f + (qltxf - pxc);
    const float wx_rb = 1.f - (qrbxf - pxc);
    const float wy_lt = 1.f + (qltyf - pyc);
    const float wy_rb = 1.f - (qrbyf - pyc);
    const int qltx = (int)qltxf, qlty = (int)qltyf;
    const int qrbx = (int)qrbxf, qrby = (int)qrbyf;
    const int cx[4] = {qltx, qrbx, qltx, qrbx};
    const int cy[4] = {qlty, qrby, qrby, qlty};
    const float gw[4] = {wx_lt * wy_lt, wx_rb * wy_rb, wx_lt * wy_rb,
                         wx_rb * wy_lt};
#pragma unroll
    for (int cc = 0; cc < 4; ++cc) {
      const bool valid =
          (cx[cc] >= 1) && (cx[cc] <= 128) && (cy[cc] >= 1) && (cy[cc] <= 128);
      si[p][n][cc] = valid ? ((cx[cc] - 1) * Ww + (cy[cc] - 1)) : 0;
      sg[p][n][cc] = valid ? gw[cc] : 0.f;
    }
  }
  __syncthreads();

  // phase 1: gather + blend -> A[pixel][n*64+ic]
  {
    const int p = t >> 4, ch4 = t & 15;
    const unsigned short* xb = xT + ((size_t)b * HW) * 64 + ch4 * 4;
#pragma unroll
    for (int n = 0; n < 9; ++n) {
      const ushort4 u0 = *(const ushort4*)(xb + (size_t)si[p][n][0] * 64);
      const ushort4 u1 = *(const ushort4*)(xb + (size_t)si[p][n][1] * 64);
      const ushort4 u2 = *(const ushort4*)(xb + (size_t)si[p][n][2] * 64);
      const ushort4 u3 = *(const ushort4*)(xb + (size_t)si[p][n][3] * 64);
      const float g0 = sg[p][n][0], g1 = sg[p][n][1], g2 = sg[p][n][2],
                  g3 = sg[p][n][3];
      float r0 = g0 * bf2f(u0.x);
      float r1 = g0 * bf2f(u0.y);
      float r2 = g0 * bf2f(u0.z);
      float r3 = g0 * bf2f(u0.w);
      r0 = fmaf(g1, bf2f(u1.x), r0); r1 = fmaf(g1, bf2f(u1.y), r1);
      r2 = fmaf(g1, bf2f(u1.z), r2); r3 = fmaf(g1, bf2f(u1.w), r3);
      r0 = fmaf(g2, bf2f(u2.x), r0); r1 = fmaf(g2, bf2f(u2.y), r1);
      r2 = fmaf(g2, bf2f(u2.z), r2); r3 = fmaf(g2, bf2f(u2.w), r3);
      r0 = fmaf(g3, bf2f(u3.x), r0); r1 = fmaf(g3, bf2f(u3.y), r1);
      r2 = fmaf(g3, bf2f(u3.z), r2); r3 = fmaf(g3, bf2f(u3.w), r3);
      ushort4 o;
      o.x = f2bf(r0); o.y = f2bf(r1); o.z = f2bf(r2); o.w = f2bf(r3);
      *(ushort4*)&A[p][n * 64 + ch4 * 4] = o;
    }
  }
  __syncthreads();

  // phase 2: MFMA. D[oc 16][pixel 16] per wave.
  {
    const int wv = t >> 6;
    const int lane = t & 63;
    const int l15 = lane & 15;
    const int quad = lane >> 4;
    const unsigned short* wrow = wtb + (size_t)(wv * 16 + l15) * 576 + quad * 8;
    const unsigned short* arow = &A[l15][quad * 8];
    f32x4 acc = {0.f, 0.f, 0.f, 0.f};
#pragma unroll
    for (int kb = 0; kb < 18; ++kb) {
      short8 af = *(const short8*)(wrow + kb * 32);
      short8 bf = *(const short8*)(arow + kb * 32);
      acc = __builtin_amdgcn_mfma_f32_16x16x32_bf16(af, bf, acc, 0, 0, 0);
    }
#pragma unroll
    for (int r = 0; r < 4; ++r) {
      const int oc = wv * 16 + quad * 4 + r;
      const size_t idx = ((size_t)(b * Cin + oc)) * HW + hw0 + l15;
      out[idx] = x[idx] + acc[r];
    }
  }
}

}  // namespace

extern "C" void kernel_launch(void* const* d_in, const int* in_sizes, int n_in,
                              void* d_out, int out_size, void* d_ws,
                              size_t ws_size, hipStream_t stream) {
  const float* x = (const float*)d_in[0];
  const float* w1 = (const float*)d_in[1];
  const float* g1 = (const float*)d_in[2];
  const float* b1 = (const float*)d_in[3];
  const float* m1 = (const float*)d_in[4];
  const float* v1 = (const float*)d_in[5];
  const float* wdw = (const float*)d_in[6];
  const float* g2 = (const float*)d_in[7];
  const float* b2 = (const float*)d_in[8];
  const float* m2 = (const float*)d_in[9];
  const float* v2 = (const float*)d_in[10];
  const float* w2 = (const float*)d_in[11];
  const float* g3 = (const float*)d_in[12];
  const float* b3 = (const float*)d_in[13];
  const float* m3 = (const float*)d_in[14];
  const float* v3 = (const float*)d_in[15];
  const float* wout = (const float*)d_in[16];
  float* out = (float*)d_out;

  char* ws = (char*)d_ws;
  unsigned short* wtb = (unsigned short*)ws;           // 73,728 B (pad 81920)
  unsigned short* xT = (unsigned short*)(ws + 81920);  // 4,194,304 B
  float* offb = (float*)(ws + 81920 + 4194304);        // 4,718,592 B

  k_pre<<<656, 256, 0, stream>>>(x, xT, wout, wtb);
  k_off<<<512, 128, 0, stream>>>(x, w1, g1, b1, m1, v1, wdw, g2, b2, m2, v2,
                                 w2, g3, b3, m3, v3, offb);
  k_main<<<2048, 256, 0, stream>>>(x, xT, offb, wtb, out);
}